// Round 2
// baseline (2055.771 us; speedup 1.0000x reference)
//
#include <hip/hip_runtime.h>
#include <hip/hip_fp16.h>

#define TOTAL 131072
#define SEGN  256
#define FEAT  78
#define FPAD  96
#define HID   1024
#define NCLS  10

typedef __attribute__((ext_vector_type(8))) short short8;
typedef __attribute__((ext_vector_type(4))) float floatx4;

typedef __attribute__((address_space(1))) void gvoid_t;
typedef __attribute__((address_space(3))) void svoid_t;

__device__ __forceinline__ void async_copy16(const void* gsrc, void* ldst) {
    __builtin_amdgcn_global_load_lds((gvoid_t*)(void*)gsrc, (svoid_t*)ldst, 16, 0, 0);
}

// ---------------- conversion kernels ----------------

// x slab [rows, FEAT] fp32 -> [rows, FPAD] fp16 (zero-padded cols)
__global__ void conv_x_slab(const float* __restrict__ x, __half* __restrict__ xb,
                            int row0, int rows) {
    int idx = blockIdx.x * 256 + threadIdx.x;
    if (idx >= rows * FPAD) return;
    int col = idx % FPAD;
    int r   = idx / FPAD;
    float v = (col < FEAT) ? x[(size_t)(row0 + r) * FEAT + col] : 0.0f;
    xb[idx] = __float2half(v);
}

// W [K,N] fp32 row-major -> Wt [N,Kpad] fp16 row-major (transposed, zero-padded K)
__global__ void conv_wt_kernel(const float* __restrict__ W, __half* __restrict__ Wt,
                               int K, int N, int Kpad) {
    int idx = blockIdx.x * 256 + threadIdx.x;
    if (idx >= N * Kpad) return;
    int k = idx % Kpad;
    int n = idx / Kpad;
    float v = (k < K) ? W[(size_t)k * N + n] : 0.0f;
    Wt[idx] = __float2half(v);
}

// ---------------- main GEMM: C = act(A @ Bt^T + bias) ----------------
// A [M,K] f16 row-major, Bt [N,K] f16 row-major, C [M,N] f16, bias fp32[N]
// 128x128 tile, BK=32, 256 threads (4 waves), mfma_f32_16x16x32_f16

__global__ __launch_bounds__(256, 2)
void gemm_f16(const __half* __restrict__ A, const __half* __restrict__ Bt,
              __half* __restrict__ C, const float* __restrict__ bias,
              int M, int N, int K, int relu_flag)
{
    __shared__ __align__(16) short lds_a[128 * 32];
    __shared__ __align__(16) short lds_b[128 * 32];
    const int t    = threadIdx.x;
    const int bn   = blockIdx.x;      // N/128 (fast) -> concurrent blocks share A stripe
    const int bm   = blockIdx.y;      // M/128
    const size_t m0 = (size_t)bm * 128;
    const size_t n0 = (size_t)bn * 128;
    const int wave = t >> 6, lane = t & 63;
    const int wm = (wave >> 1) << 6;  // wave row quadrant (0/64)
    const int wn = (wave & 1) << 6;   // wave col quadrant (0/64)
    const int l16 = lane & 15, q = lane >> 4;

    floatx4 acc[4][4] = {};

    // staging chunk mapping: chunk c (16B = 8 f16): row = c>>2, k-chunk = c&3
    const int c0 = t, c1 = t + 256;
    const __half* a0 = A  + (m0 + (size_t)(c0 >> 2)) * K + (c0 & 3) * 8;
    const __half* a1 = A  + (m0 + (size_t)(c1 >> 2)) * K + (c1 & 3) * 8;
    const __half* b0 = Bt + (n0 + (size_t)(c0 >> 2)) * K + (c0 & 3) * 8;
    const __half* b1 = Bt + (n0 + (size_t)(c1 >> 2)) * K + (c1 & 3) * 8;
    short* la0 = &lds_a[c0 * 8];
    short* la1 = &lds_a[c1 * 8];
    short* lb0 = &lds_b[c0 * 8];
    short* lb1 = &lds_b[c1 * 8];

    for (int k0 = 0; k0 < K; k0 += 32) {
        __syncthreads();
        async_copy16(a0 + k0, la0);
        async_copy16(a1 + k0, la1);
        async_copy16(b0 + k0, lb0);
        async_copy16(b1 + k0, lb1);
        __syncthreads();

        short8 af[4], bf[4];
#pragma unroll
        for (int i = 0; i < 4; ++i)
            af[i] = *(const short8*)&lds_a[(wm + i * 16 + l16) * 32 + q * 8];
#pragma unroll
        for (int i = 0; i < 4; ++i)
            bf[i] = *(const short8*)&lds_b[(wn + i * 16 + l16) * 32 + q * 8];

#pragma unroll
        for (int mi = 0; mi < 4; ++mi)
#pragma unroll
            for (int ni = 0; ni < 4; ++ni)
                acc[mi][ni] = __builtin_amdgcn_mfma_f32_16x16x32_f16(
                    af[mi], bf[ni], acc[mi][ni], 0, 0, 0);
    }

    // epilogue: within a 16x16 tile: col = l16, row = q*4 + r
#pragma unroll
    for (int ni = 0; ni < 4; ++ni) {
        const int col = (int)n0 + wn + ni * 16 + l16;
        const float bv = bias[col];
#pragma unroll
        for (int mi = 0; mi < 4; ++mi) {
            const size_t row0 = m0 + wm + mi * 16 + q * 4;
#pragma unroll
            for (int r = 0; r < 4; ++r) {
                float v = acc[mi][ni][r] + bv;
                if (relu_flag) v = fmaxf(v, 0.0f);
                C[(row0 + r) * N + col] = __float2half(v);
            }
        }
    }
}

// ---------------- segment offsets ----------------

__global__ void seg_offsets_kernel(const int* __restrict__ lengths, int* __restrict__ off) {
    if (blockIdx.x == 0 && threadIdx.x == 0) {
        int a = 0;
        off[0] = 0;
        for (int i = 0; i < SEGN; ++i) { a += lengths[i]; off[i + 1] = a; }
    }
}

// ---------------- fused score + exp-weight + pooling accumulate (per slab) ----
// For each segment s intersecting the slab:
//   for frames i: e_i = exp(relu(h4_i . W5 + b5))  [no max-subtract: scores >= 0, tiny]
//   pooled_num[s][:] += sum_i e_i * h4_i[:] ;  denom[s] += sum_i e_i
// One block per segment; slabs are launched sequentially -> no atomics needed.

__global__ void score_pool_kernel(const __half* __restrict__ h4, int slab_beg, int slab_rows,
                                  const float* __restrict__ W5, const float* __restrict__ b5,
                                  const int* __restrict__ segoff,
                                  float* __restrict__ pooled_num, float* __restrict__ denom)
{
    int s = blockIdx.x, t = threadIdx.x;
    int beg = segoff[s], end = segoff[s + 1];
    if (beg < slab_beg) beg = slab_beg;
    int slab_end = slab_beg + slab_rows;
    if (end > slab_end) end = slab_end;
    if (beg >= end) return;
    int cnt = end - beg;

    __shared__ float e_sh[1024];   // max frames per (segment ∩ slab) < 1024

    const int wave = t >> 6, lane = t & 63;
    const float b5v = b5[0];

    // phase 1: scores -> exp weights, one frame per wave
    for (int f = beg + wave; f < end; f += 4) {
        const __half* row = h4 + (size_t)(f - slab_beg) * HID + lane * 16;
        const float* wv = W5 + lane * 16;
        float sacc = 0.f;
#pragma unroll
        for (int j = 0; j < 16; ++j) sacc += __half2float(row[j]) * wv[j];
#pragma unroll
        for (int o = 32; o > 0; o >>= 1) sacc += __shfl_down(sacc, o);
        if (lane == 0) {
            float sc = fmaxf(sacc + b5v, 0.0f);
            e_sh[f - beg] = expf(fminf(sc, 80.0f));
        }
    }
    __syncthreads();

    // phase 2: weighted accumulate; thread t owns cols [t*4, t*4+4)
    float a0 = 0.f, a1 = 0.f, a2 = 0.f, a3 = 0.f;
    for (int i = 0; i < cnt; ++i) {
        float e = e_sh[i];
        const __half2* r2 = (const __half2*)(h4 + (size_t)(beg - slab_beg + i) * HID + t * 4);
        float2 f0 = __half22float2(r2[0]);
        float2 f1 = __half22float2(r2[1]);
        a0 += e * f0.x; a1 += e * f0.y; a2 += e * f1.x; a3 += e * f1.y;
    }
    float* o = pooled_num + (size_t)s * HID + t * 4;
    o[0] += a0; o[1] += a1; o[2] += a2; o[3] += a3;

    if (t == 0) {
        float ds = 0.f;
        for (int i = 0; i < cnt; ++i) ds += e_sh[i];
        denom[s] += ds;
    }
}

// ---------------- finalize pooling: poolh = fp16(pooled_num / denom) ----------

__global__ void finalize_pool_kernel(const float* __restrict__ pooled_num,
                                     const float* __restrict__ denom,
                                     __half* __restrict__ poolh) {
    int s = blockIdx.x, t = threadIdx.x;
    float inv = 1.0f / denom[s];
    for (int j = t; j < HID; j += 256)
        poolh[(size_t)s * HID + j] = __float2half(pooled_num[(size_t)s * HID + j] * inv);
}

// ---------------- final head: out = z @ W7 + b7 ----------------

__global__ void final_kernel(const __half* __restrict__ z, const float* __restrict__ W7,
                             const float* __restrict__ b7, float* __restrict__ out) {
    int s = blockIdx.x, t = threadIdx.x;
    float loc[NCLS];
#pragma unroll
    for (int c = 0; c < NCLS; ++c) loc[c] = 0.f;
    for (int k = t; k < HID; k += 256) {
        float zk = __half2float(z[(size_t)s * HID + k]);
        const float* wr = W7 + k * NCLS;
#pragma unroll
        for (int c = 0; c < NCLS; ++c) loc[c] += zk * wr[c];
    }
#pragma unroll
    for (int c = 0; c < NCLS; ++c)
#pragma unroll
        for (int o = 32; o > 0; o >>= 1) loc[c] += __shfl_down(loc[c], o);
    __shared__ float accs[NCLS];
    if (t < NCLS) accs[t] = 0.f;
    __syncthreads();
    if ((t & 63) == 0)
        for (int c = 0; c < NCLS; ++c) atomicAdd(&accs[c], loc[c]);
    __syncthreads();
    if (t < NCLS) out[s * NCLS + t] = accs[t] + b7[t];
}

// ---------------- launch ----------------

extern "C" void kernel_launch(void* const* d_in, const int* in_sizes, int n_in,
                              void* d_out, int out_size, void* d_ws, size_t ws_size,
                              hipStream_t stream) {
    const float* x  = (const float*)d_in[0];
    const float* W1 = (const float*)d_in[1];
    const float* b1 = (const float*)d_in[2];
    const float* W2 = (const float*)d_in[3];
    const float* b2 = (const float*)d_in[4];
    const float* W3 = (const float*)d_in[5];
    const float* b3 = (const float*)d_in[6];
    const float* W4 = (const float*)d_in[7];
    const float* b4 = (const float*)d_in[8];
    const float* W5 = (const float*)d_in[9];
    const float* b5 = (const float*)d_in[10];
    const float* W6 = (const float*)d_in[11];
    const float* b6 = (const float*)d_in[12];
    const float* W7 = (const float*)d_in[13];
    const float* b7 = (const float*)d_in[14];
    const int* lengths = (const int*)d_in[15];
    float* out = (float*)d_out;

    // ---- adaptive workspace layout (same arithmetic every call -> capture-safe) ----
    char* ws = (char*)d_ws;
    size_t off = 0;
    auto take = [&](size_t bytes) -> char* {
        char* p = ws + off;
        off = (off + bytes + 255) & ~(size_t)255;
        return p;
    };
    __half* w1t   = (__half*)take((size_t)HID * FPAD * 2);
    __half* w2t   = (__half*)take((size_t)HID * HID * 2);
    __half* w3t   = (__half*)take((size_t)HID * HID * 2);
    __half* w4t   = (__half*)take((size_t)HID * HID * 2);
    __half* w6t   = (__half*)take((size_t)HID * HID * 2);
    int*    segoff = (int*)take((SEGN + 1) * 4);
    float*  pooled = (float*)take((size_t)SEGN * HID * 4);
    float*  denom  = (float*)take(SEGN * 4);
    __half* poolh  = (__half*)take((size_t)SEGN * HID * 2);
    __half* z      = (__half*)take((size_t)SEGN * HID * 2);

    // slab rows: largest power-of-two divisor of TOTAL that fits
    int R = TOTAL;
    while (R > 1024) {
        size_t need = off + (size_t)R * FPAD * 2 + 2 * (size_t)R * HID * 2 + 3 * 256;
        if (need <= ws_size) break;
        R >>= 1;
    }
    __half* slabX = (__half*)take((size_t)R * FPAD * 2);
    __half* slabA = (__half*)take((size_t)R * HID * 2);
    __half* slabB = (__half*)take((size_t)R * HID * 2);

    // ---- preliminaries ----
    seg_offsets_kernel<<<1, 64, 0, stream>>>(lengths, segoff);
    hipMemsetAsync(pooled, 0, (size_t)SEGN * HID * 4, stream);
    hipMemsetAsync(denom, 0, SEGN * 4, stream);

    conv_wt_kernel<<<(HID * FPAD + 255) / 256, 256, 0, stream>>>(W1, w1t, FEAT, HID, FPAD);
    conv_wt_kernel<<<(HID * HID + 255) / 256, 256, 0, stream>>>(W2, w2t, HID, HID, HID);
    conv_wt_kernel<<<(HID * HID + 255) / 256, 256, 0, stream>>>(W3, w3t, HID, HID, HID);
    conv_wt_kernel<<<(HID * HID + 255) / 256, 256, 0, stream>>>(W4, w4t, HID, HID, HID);
    conv_wt_kernel<<<(HID * HID + 255) / 256, 256, 0, stream>>>(W6, w6t, HID, HID, HID);

    // ---- slabbed trunk + fused score/pool ----
    dim3 gSlab(HID / 128, R / 128);
    for (int sb = 0; sb < TOTAL; sb += R) {
        conv_x_slab<<<(R * FPAD + 255) / 256, 256, 0, stream>>>(x, slabX, sb, R);
        gemm_f16<<<gSlab, 256, 0, stream>>>(slabX, w1t, slabA, b1, R, HID, FPAD, 1);
        gemm_f16<<<gSlab, 256, 0, stream>>>(slabA, w2t, slabB, b2, R, HID, HID, 1);
        gemm_f16<<<gSlab, 256, 0, stream>>>(slabB, w3t, slabA, b3, R, HID, HID, 1);
        gemm_f16<<<gSlab, 256, 0, stream>>>(slabA, w4t, slabB, b4, R, HID, HID, 1);
        score_pool_kernel<<<SEGN, 256, 0, stream>>>(slabB, sb, R, W5, b5, segoff, pooled, denom);
    }

    // ---- head ----
    finalize_pool_kernel<<<SEGN, 256, 0, stream>>>(pooled, denom, poolh);
    dim3 gHead(HID / 128, SEGN / 128);
    gemm_f16<<<gHead, 256, 0, stream>>>(poolh, w6t, z, b6, SEGN, HID, HID, 1);
    final_kernel<<<SEGN, 256, 0, stream>>>(z, W7, b7, out);
}